// Round 2
// baseline (122.357 us; speedup 1.0000x reference)
//
#include <hip/hip_runtime.h>
#include <hip/hip_bf16.h>

#define BB 2048
#define NN 4096
#define MM 4096
#define KK 8
#define HH 64

using f32x4  = __attribute__((ext_vector_type(4))) float;
using bf16x8 = __attribute__((ext_vector_type(8))) short;

__device__ __forceinline__ unsigned short f2bf(float f) {
    union { float f; unsigned int u; } v; v.f = f;
    unsigned int r = ((v.u >> 16) & 1u) + 0x7FFFu;   // round-to-nearest-even
    return (unsigned short)((v.u + r) >> 16);
}

// ---- 1) quantize ram_tables rows: scale = max(max|w|,1e-6)/127; dq = clip(rint(w/scale))*scale
__global__ void k_quant_tables(const float* __restrict__ tab, float* __restrict__ dq) {
    int row = blockIdx.x;
    int t = threadIdx.x;
    float v = tab[(size_t)row * 256 + t];
    float a = fabsf(v);
    #pragma unroll
    for (int off = 32; off; off >>= 1) a = fmaxf(a, __shfl_xor(a, off));
    __shared__ float red[4];
    if ((t & 63) == 0) red[t >> 6] = a;
    __syncthreads();
    float m = fmaxf(fmaxf(red[0], red[1]), fmaxf(red[2], red[3]));
    float scale = fmaxf(m, 1e-6f) / 127.0f;
    float q = rintf(v / scale);
    q = fminf(fmaxf(q, -127.0f), 127.0f);
    dq[(size_t)row * 256 + t] = q * scale;
}

// ---- 2) quantize halt_w (one row of 4096)
__global__ void k_quant_halt(const float* __restrict__ hw, float* __restrict__ wdq) {
    int t = threadIdx.x;
    float vals[16];
    float a = 0.f;
    #pragma unroll
    for (int i = 0; i < 16; ++i) { vals[i] = hw[t * 16 + i]; a = fmaxf(a, fabsf(vals[i])); }
    #pragma unroll
    for (int off = 32; off; off >>= 1) a = fmaxf(a, __shfl_xor(a, off));
    __shared__ float red[4];
    if ((t & 63) == 0) red[t >> 6] = a;
    __syncthreads();
    float m = fmaxf(fmaxf(red[0], red[1]), fmaxf(red[2], red[3]));
    float scale = fmaxf(m, 1e-6f) / 127.0f;
    #pragma unroll
    for (int i = 0; i < 16; ++i) {
        float q = rintf(vals[i] / scale);
        q = fminf(fmaxf(q, -127.0f), 127.0f);
        wdq[t * 16 + i] = q * scale;
    }
}

// ---- 3) pack sign bits of x: one u64 word (64 consecutive cols) per wave iteration via ballot
__global__ void k_bits(const float* __restrict__ x, unsigned long long* __restrict__ bits) {
    int lane = threadIdx.x & 63;
    int wave = (blockIdx.x * blockDim.x + threadIdx.x) >> 6;
    int nwaves = (gridDim.x * blockDim.x) >> 6;
    const int total = BB * (NN / 64);
    for (int w = wave; w < total; w += nwaves) {
        float v = x[(size_t)w * 64 + lane];   // word layout == row-major x layout
        unsigned long long msk = __ballot(v > 0.0f);
        if (lane == 0) bits[w] = msk;
    }
}

// ---- 3b) pre-convert w1 to bf16
__global__ void k_w1bf(const float* __restrict__ w1, short* __restrict__ w1b) {
    int i = blockIdx.x * blockDim.x + threadIdx.x;  // 0 .. 64*4096/4
    f32x4 v = *(const f32x4*)(w1 + (size_t)i * 4);
    short4 o;
    o.x = (short)f2bf(v[0]); o.y = (short)f2bf(v[1]);
    o.z = (short)f2bf(v[2]); o.w = (short)f2bf(v[3]);
    *(short4*)(w1b + (size_t)i * 4) = o;
}

// ---- 4) h-partial GEMM: x(2048x4096) @ w1^T(4096x64), k-split by 8, bf16 MFMA 16x16x32
__global__ __launch_bounds__(256) void k_gemm(const float* __restrict__ x,
                                              const short* __restrict__ w1b,
                                              float* __restrict__ hpart) {
    int wid  = threadIdx.x >> 6;
    int lane = threadIdx.x & 63;
    int b0   = blockIdx.x * 64 + wid * 16;  // 32 blocks in x
    int k0   = blockIdx.y * 512;            // 8 k-splits
    int row  = lane & 15;
    int koff = (lane >> 4) * 8;

    const float* xp = x + (size_t)(b0 + row) * NN + k0 + koff;
    f32x4 acc[4] = {};

    for (int kk = 0; kk < 16; ++kk) {
        const float* xa = xp + kk * 32;
        f32x4 a0 = *(const f32x4*)(xa);
        f32x4 a1 = *(const f32x4*)(xa + 4);
        bf16x8 af;
        af[0] = (short)f2bf(a0[0]); af[1] = (short)f2bf(a0[1]);
        af[2] = (short)f2bf(a0[2]); af[3] = (short)f2bf(a0[3]);
        af[4] = (short)f2bf(a1[0]); af[5] = (short)f2bf(a1[1]);
        af[6] = (short)f2bf(a1[2]); af[7] = (short)f2bf(a1[3]);
        #pragma unroll
        for (int t = 0; t < 4; ++t) {
            const short* wp = w1b + (size_t)(t * 16 + row) * NN + k0 + kk * 32 + koff;
            bf16x8 bf = *(const bf16x8*)wp;
            acc[t] = __builtin_amdgcn_mfma_f32_16x16x32_bf16(af, bf, acc[t], 0, 0, 0);
        }
    }

    int ks = blockIdx.y;
    #pragma unroll
    for (int t = 0; t < 4; ++t) {
        #pragma unroll
        for (int r = 0; r < 4; ++r) {
            int b = b0 + (lane >> 4) * 4 + r;       // C/D: row=(lane>>4)*4+reg
            int h = t * 16 + (lane & 15);           // C/D: col=lane&15
            hpart[((size_t)ks * BB + b) * HH + h] = acc[t][r];
        }
    }
}

// ---- 5) reduce k-splits, +b1, relu, dot w2, +b2 -> out[2b] (f32); one wave per b
__global__ void k_engage(const float* __restrict__ hpart, const float* __restrict__ b1,
                         const float* __restrict__ w2, const float* __restrict__ b2,
                         float* __restrict__ out) {
    int t = threadIdx.x;
    int h = t & 63;
    int b = blockIdx.x * 4 + (t >> 6);
    float s = 0.f;
    #pragma unroll
    for (int ks = 0; ks < 8; ++ks) s += hpart[((size_t)ks * BB + b) * HH + h];
    s += b1[h];
    s = fmaxf(s, 0.f);
    s *= w2[h];
    #pragma unroll
    for (int off = 32; off; off >>= 1) s += __shfl_xor(s, off);
    if (h == 0) out[b * 2] = s + b2[0];
}

// ---- 6) halt partial: lane = b, bits staged in LDS (u32 words, XOR swizzle), fused table gather + dot
__global__ __launch_bounds__(256) void k_halt(const unsigned int* __restrict__ bits32,
                                              const int* __restrict__ conn,
                                              const float* __restrict__ tdq,
                                              const float* __restrict__ wdq,
                                              float* __restrict__ hpartial) {
    __shared__ unsigned int lb[64 * 128];   // 32 KB: 64 b-rows x 128 u32 words
    int b0 = blockIdx.x * 64;
    int t = threadIdx.x;
    for (int i = t; i < 64 * 128; i += 256) {
        int r = i >> 7, w = i & 127;
        lb[r * 128 + (w ^ (r & 31))] = bits32[(size_t)(b0 + r) * 128 + w];
    }
    __syncthreads();

    int lane = t & 63;
    int wid  = t >> 6;
    int m0 = blockIdx.y * 512 + wid * 128;
    const unsigned int* myrow = lb + lane * 128;
    int sw = lane & 31;
    float acc = 0.f;

    for (int mi = 0; mi < 128; ++mi) {
        int m = m0 + mi;
        int addr = 0;
        #pragma unroll
        for (int k = 0; k < 8; ++k) {
            int c = conn[m * 8 + k];                       // uniform -> s_load
            unsigned int word = myrow[(c >> 5) ^ sw];      // swizzled, conflict-free
            addr |= (int)((word >> (c & 31)) & 1u) << k;
        }
        acc += tdq[(size_t)m * 256 + addr] * wdq[m];
    }
    hpartial[(size_t)(b0 + lane) * 32 + blockIdx.y * 4 + wid] = acc;
}

// ---- 7) reduce halt partials -> out[2b+1]
__global__ void k_halt_reduce(const float* __restrict__ hpartial, const float* __restrict__ halt_b,
                              float* __restrict__ out) {
    int b = blockIdx.x * 256 + threadIdx.x;
    float s = halt_b[0];
    #pragma unroll
    for (int j = 0; j < 32; ++j) s += hpartial[(size_t)b * 32 + j];
    out[b * 2 + 1] = s;
}

extern "C" void kernel_launch(void* const* d_in, const int* in_sizes, int n_in,
                              void* d_out, int out_size, void* d_ws, size_t ws_size,
                              hipStream_t stream) {
    const float* x    = (const float*)d_in[0];
    const float* tab  = (const float*)d_in[1];
    const float* w1   = (const float*)d_in[2];
    const float* b1   = (const float*)d_in[3];
    const float* w2   = (const float*)d_in[4];
    const float* b2   = (const float*)d_in[5];
    const float* hw   = (const float*)d_in[6];
    const float* hb   = (const float*)d_in[7];
    const int*   conn = (const int*)d_in[8];
    float* out = (float*)d_out;

    char* ws = (char*)d_ws;
    float* tdq                 = (float*)(ws);                 // 4,194,304 B
    float* wdq                 = (float*)(ws + 4194304);       //    16,384 B
    unsigned long long* bits   = (unsigned long long*)(ws + 4210688); // 1,048,576 B
    float* hpart               = (float*)(ws + 5259264);       // 4,194,304 B
    float* haltp               = (float*)(ws + 9453568);       //   262,144 B
    short* w1b                 = (short*)(ws + 9715712);       //   524,288 B

    k_quant_tables<<<MM, 256, 0, stream>>>(tab, tdq);
    k_quant_halt<<<1, 256, 0, stream>>>(hw, wdq);
    k_bits<<<512, 256, 0, stream>>>(x, bits);
    k_w1bf<<<(HH * NN / 4 + 255) / 256, 256, 0, stream>>>(w1, w1b);

    dim3 gg(32, 8);
    k_gemm<<<gg, 256, 0, stream>>>(x, w1b, hpart);
    k_engage<<<BB / 4, 256, 0, stream>>>(hpart, b1, w2, b2, out);

    dim3 gh(32, 8);
    k_halt<<<gh, 256, 0, stream>>>((const unsigned int*)bits, conn, tdq, wdq, haltp);
    k_halt_reduce<<<BB / 256, 256, 0, stream>>>(haltp, hb, out);
}

// Round 3
// 96.964 us; speedup vs baseline: 1.2619x; 1.2619x over previous
//
#include <hip/hip_runtime.h>
#include <hip/hip_bf16.h>

#define BB 2048
#define NN 4096
#define MM 4096
#define HH 64

using f32x4  = __attribute__((ext_vector_type(4))) float;
using bf16x8 = __attribute__((ext_vector_type(8))) short;

__device__ __forceinline__ unsigned short f2bf(float f) {
    union { float f; unsigned int u; } v; v.f = f;
    unsigned int r = ((v.u >> 16) & 1u) + 0x7FFFu;   // round-to-nearest-even
    return (unsigned short)((v.u + r) >> 16);
}

// ============ prep: [0,256) bits-transpose | [256,4352) table quant | [4352,4480) w1->bf16 | 4480 halt quant
__global__ __launch_bounds__(256) void k_prep(const float* __restrict__ x,
                                              const float* __restrict__ tab,
                                              const float* __restrict__ w1,
                                              const float* __restrict__ hw,
                                              unsigned int* __restrict__ bits_t,
                                              float* __restrict__ tdq,
                                              short* __restrict__ w1b,
                                              float* __restrict__ wdq) {
    __shared__ unsigned int tb[64][17];
    __shared__ float red[4];
    int id = blockIdx.x;
    int t = threadIdx.x;
    int lane = t & 63;
    int wid = t >> 6;

    if (id < 256) {
        // ---- sign bits of x, written TRANSPOSED: bits_t[word][b], word = col/32
        int bx = id >> 3, seg = id & 7;
        int b0 = bx * 64;
        int w0 = seg * 16;                      // 16 u32 words = 512 columns
        for (int i = 0; i < 16; ++i) {
            int bl = wid * 16 + i;
            #pragma unroll
            for (int ch = 0; ch < 8; ++ch) {    // 8 x 64 cols
                float v = x[(size_t)(b0 + bl) * NN + w0 * 32 + ch * 64 + lane];
                unsigned long long msk = __ballot(v > 0.0f);
                if (lane == 0) {
                    tb[bl][ch * 2]     = (unsigned int)msk;
                    tb[bl][ch * 2 + 1] = (unsigned int)(msk >> 32);
                }
            }
        }
        __syncthreads();
        #pragma unroll
        for (int j = 0; j < 4; ++j) {
            int w = wid * 4 + j;
            bits_t[(size_t)(w0 + w) * BB + b0 + lane] = tb[lane][w];
        }
    } else if (id < 4352) {
        // ---- quantize ram_tables row
        int row = id - 256;
        float v = tab[(size_t)row * 256 + t];
        float a = fabsf(v);
        #pragma unroll
        for (int off = 32; off; off >>= 1) a = fmaxf(a, __shfl_xor(a, off));
        if (lane == 0) red[wid] = a;
        __syncthreads();
        float m = fmaxf(fmaxf(red[0], red[1]), fmaxf(red[2], red[3]));
        float scale = fmaxf(m, 1e-6f) / 127.0f;
        float q = rintf(v / scale);
        q = fminf(fmaxf(q, -127.0f), 127.0f);
        tdq[(size_t)row * 256 + t] = q * scale;
    } else if (id < 4480) {
        // ---- w1 -> bf16
        int base = (id - 4352) * 2048 + t * 8;
        f32x4 a0 = *(const f32x4*)(w1 + base);
        f32x4 a1 = *(const f32x4*)(w1 + base + 4);
        short4 o0, o1;
        o0.x = (short)f2bf(a0[0]); o0.y = (short)f2bf(a0[1]);
        o0.z = (short)f2bf(a0[2]); o0.w = (short)f2bf(a0[3]);
        o1.x = (short)f2bf(a1[0]); o1.y = (short)f2bf(a1[1]);
        o1.z = (short)f2bf(a1[2]); o1.w = (short)f2bf(a1[3]);
        *(short4*)(w1b + base) = o0;
        *(short4*)(w1b + base + 4) = o1;
    } else {
        // ---- quantize halt_w (4096 elems, one block)
        float vals[16];
        float a = 0.f;
        #pragma unroll
        for (int i = 0; i < 16; ++i) { vals[i] = hw[t * 16 + i]; a = fmaxf(a, fabsf(vals[i])); }
        #pragma unroll
        for (int off = 32; off; off >>= 1) a = fmaxf(a, __shfl_xor(a, off));
        if (lane == 0) red[wid] = a;
        __syncthreads();
        float m = fmaxf(fmaxf(red[0], red[1]), fmaxf(red[2], red[3]));
        float scale = fmaxf(m, 1e-6f) / 127.0f;
        #pragma unroll
        for (int i = 0; i < 16; ++i) {
            float q = rintf(vals[i] / scale);
            q = fminf(fmaxf(q, -127.0f), 127.0f);
            wdq[t * 16 + i] = q * scale;
        }
    }
}

// ============ main: [0,128) gemm k-split | [128,1152) halt partials
__global__ __launch_bounds__(256) void k_main(const float* __restrict__ x,
                                              const short* __restrict__ w1b,
                                              const unsigned int* __restrict__ bits_t,
                                              const int* __restrict__ conn,
                                              const float* __restrict__ tdq,
                                              const float* __restrict__ wdq,
                                              float* __restrict__ hpart,
                                              float* __restrict__ haltp) {
    int id = blockIdx.x;
    int t = threadIdx.x;
    int lane = t & 63;
    int wid = t >> 6;

    if (id < 128) {
        // ---- x(2048x4096) @ w1^T -> hpart[ks][b][h], bf16 MFMA 16x16x32, k-split 4
        int bx = id & 31, ks = id >> 5;
        int b0 = bx * 64 + wid * 16;
        int k0 = ks * 1024;
        int row = lane & 15;
        int koff = (lane >> 4) * 8;

        const float* xp = x + (size_t)(b0 + row) * NN + k0 + koff;
        f32x4 acc[4] = {};

        for (int kk = 0; kk < 32; ++kk) {
            const float* xa = xp + kk * 32;
            f32x4 a0 = *(const f32x4*)(xa);
            f32x4 a1 = *(const f32x4*)(xa + 4);
            bf16x8 af;
            af[0] = (short)f2bf(a0[0]); af[1] = (short)f2bf(a0[1]);
            af[2] = (short)f2bf(a0[2]); af[3] = (short)f2bf(a0[3]);
            af[4] = (short)f2bf(a1[0]); af[5] = (short)f2bf(a1[1]);
            af[6] = (short)f2bf(a1[2]); af[7] = (short)f2bf(a1[3]);
            #pragma unroll
            for (int h = 0; h < 4; ++h) {
                const short* wp = w1b + (size_t)(h * 16 + row) * NN + k0 + kk * 32 + koff;
                bf16x8 bf = *(const bf16x8*)wp;
                acc[h] = __builtin_amdgcn_mfma_f32_16x16x32_bf16(af, bf, acc[h], 0, 0, 0);
            }
        }
        #pragma unroll
        for (int h = 0; h < 4; ++h) {
            #pragma unroll
            for (int r = 0; r < 4; ++r) {
                int b = b0 + (lane >> 4) * 4 + r;     // C/D: row=(lane>>4)*4+reg
                int hh = h * 16 + (lane & 15);        // C/D: col=lane&15
                hpart[((size_t)ks * BB + b) * HH + hh] = acc[h][r];
            }
        }
    } else {
        // ---- halt partials: lane=b (coalesced bits_t reads), 32 m per wave
        int hid = id - 128;
        int hx = hid & 31, hy = hid >> 5;             // hy in [0,32)
        int b = hx * 64 + lane;
        int m0 = hy * 128 + wid * 32;
        float acc = 0.f;
        #pragma unroll 4
        for (int mi = 0; mi < 32; ++mi) {
            int m = m0 + mi;
            int addr = 0;
            #pragma unroll
            for (int k = 0; k < 8; ++k) {
                int c = conn[m * 8 + k];                               // uniform -> s_load
                unsigned int w = bits_t[(size_t)(c >> 5) * BB + b];    // coalesced, L1-hit
                addr |= (int)((w >> (c & 31)) & 1u) << k;
            }
            acc += tdq[(size_t)m * 256 + addr] * wdq[m];
        }
        haltp[(size_t)(hy * 4 + wid) * BB + b] = acc;                  // coalesced
    }
}

// ============ finish: [0,512) engage reduce | [512,520) halt reduce
__global__ __launch_bounds__(256) void k_finish(const float* __restrict__ hpart,
                                                const float* __restrict__ b1,
                                                const float* __restrict__ w2,
                                                const float* __restrict__ b2,
                                                const float* __restrict__ haltp,
                                                const float* __restrict__ hb,
                                                float* __restrict__ out) {
    int id = blockIdx.x;
    int t = threadIdx.x;
    if (id < 512) {
        int h = t & 63;
        int b = id * 4 + (t >> 6);
        float s = 0.f;
        #pragma unroll
        for (int ks = 0; ks < 4; ++ks) s += hpart[((size_t)ks * BB + b) * HH + h];
        s += b1[h];
        s = fmaxf(s, 0.f);
        s *= w2[h];
        #pragma unroll
        for (int off = 32; off; off >>= 1) s += __shfl_xor(s, off);
        if (h == 0) out[b * 2] = s + b2[0];
    } else {
        int b = (id - 512) * 256 + t;
        float s = hb[0];
        #pragma unroll 8
        for (int j = 0; j < 128; ++j) s += haltp[(size_t)j * BB + b];  // coalesced
        out[b * 2 + 1] = s;
    }
}

extern "C" void kernel_launch(void* const* d_in, const int* in_sizes, int n_in,
                              void* d_out, int out_size, void* d_ws, size_t ws_size,
                              hipStream_t stream) {
    const float* x    = (const float*)d_in[0];
    const float* tab  = (const float*)d_in[1];
    const float* w1   = (const float*)d_in[2];
    const float* b1   = (const float*)d_in[3];
    const float* w2   = (const float*)d_in[4];
    const float* b2   = (const float*)d_in[5];
    const float* hw   = (const float*)d_in[6];
    const float* hb   = (const float*)d_in[7];
    const int*   conn = (const int*)d_in[8];
    float* out = (float*)d_out;

    char* ws = (char*)d_ws;
    float*        tdq    = (float*)(ws);                      // 4,194,304 B
    float*        wdq    = (float*)(ws + 4194304);            //    16,384 B
    unsigned int* bits_t = (unsigned int*)(ws + 4210688);     // 1,048,576 B
    float*        hpart  = (float*)(ws + 5259264);            // 2,097,152 B
    float*        haltp  = (float*)(ws + 7356416);            // 1,048,576 B
    short*        w1b    = (short*)(ws + 8404992);            //   524,288 B  (end 8,929,280)

    k_prep<<<4481, 256, 0, stream>>>(x, tab, w1, hw, bits_t, tdq, w1b, wdq);
    k_main<<<1152, 256, 0, stream>>>(x, w1b, bits_t, conn, tdq, wdq, hpart, haltp);
    k_finish<<<520, 256, 0, stream>>>(hpart, b1, w2, b2, haltp, hb, out);
}

// Round 4
// 59.317 us; speedup vs baseline: 2.0628x; 1.6347x over previous
//
#include <hip/hip_runtime.h>
#include <hip/hip_bf16.h>

#define BB 2048
#define NN 4096
#define MM 4096
#define HH 64

using f32x4  = __attribute__((ext_vector_type(4))) float;
using bf16x8 = __attribute__((ext_vector_type(8))) short;

__device__ __forceinline__ unsigned short f2bf(float f) {
    union { float f; unsigned int u; } v; v.f = f;
    unsigned int r = ((v.u >> 16) & 1u) + 0x7FFFu;   // round-to-nearest-even
    return (unsigned short)((v.u + r) >> 16);
}

__device__ __forceinline__ float bf2f(unsigned short s) {
    union { unsigned int u; float f; } v; v.u = ((unsigned int)s) << 16;
    return v.f;
}

// ============ prep:
//   [0,1024)    bits pack (transposed layout), 1 word/thread, ballot-free
//   [1024,2048) table quant -> bf16, 4 rows/block (1 row/wave)
//   [2048,2176) w1 -> bf16
//   2176        halt_w quant
__global__ __launch_bounds__(256) void k_prep(const float* __restrict__ x,
                                              const float* __restrict__ tab,
                                              const float* __restrict__ w1,
                                              const float* __restrict__ hw,
                                              unsigned int* __restrict__ bits_t,
                                              unsigned short* __restrict__ tdq,
                                              short* __restrict__ w1b,
                                              float* __restrict__ wdq) {
    int id = blockIdx.x;
    int t = threadIdx.x;
    int lane = t & 63;
    int wid = t >> 6;

    if (id < 1024) {
        // ---- sign bits: thread packs one u32 word from its own 32 consecutive cols
        int w  = id >> 3;                 // word index [0,128)
        int b  = (id & 7) * 256 + t;      // batch row
        const float* xp = x + (size_t)b * NN + w * 32;
        f32x4 v[8];
        #pragma unroll
        for (int j = 0; j < 8; ++j) v[j] = *(const f32x4*)(xp + j * 4);
        unsigned int word = 0;
        #pragma unroll
        for (int j = 0; j < 8; ++j) {
            #pragma unroll
            for (int e = 0; e < 4; ++e)
                word |= (v[j][e] > 0.0f ? 1u : 0u) << (j * 4 + e);
        }
        bits_t[(size_t)w * BB + b] = word;   // coalesced
    } else if (id < 2048) {
        // ---- quantize ram_tables: one row per wave, f32x4 per lane
        int row = (id - 1024) * 4 + wid;
        f32x4 v = *(const f32x4*)(tab + (size_t)row * 256 + lane * 4);
        float a = fmaxf(fmaxf(fabsf(v[0]), fabsf(v[1])), fmaxf(fabsf(v[2]), fabsf(v[3])));
        #pragma unroll
        for (int off = 32; off; off >>= 1) a = fmaxf(a, __shfl_xor(a, off));
        float scale = fmaxf(a, 1e-6f) / 127.0f;
        short4 o;
        #pragma unroll
        for (int e = 0; e < 4; ++e) {
            float q = rintf(v[e] / scale);
            q = fminf(fmaxf(q, -127.0f), 127.0f);
            ((short*)&o)[e] = (short)f2bf(q * scale);
        }
        *(short4*)(tdq + (size_t)row * 256 + lane * 4) = o;
    } else if (id < 2176) {
        // ---- w1 -> bf16
        int base = (id - 2048) * 2048 + t * 8;
        f32x4 a0 = *(const f32x4*)(w1 + base);
        f32x4 a1 = *(const f32x4*)(w1 + base + 4);
        short4 o0, o1;
        o0.x = (short)f2bf(a0[0]); o0.y = (short)f2bf(a0[1]);
        o0.z = (short)f2bf(a0[2]); o0.w = (short)f2bf(a0[3]);
        o1.x = (short)f2bf(a1[0]); o1.y = (short)f2bf(a1[1]);
        o1.z = (short)f2bf(a1[2]); o1.w = (short)f2bf(a1[3]);
        *(short4*)(w1b + base) = o0;
        *(short4*)(w1b + base + 4) = o1;
    } else {
        // ---- quantize halt_w (4096 elems, one block), wdq stays f32
        __shared__ float red[4];
        float vals[16];
        float a = 0.f;
        #pragma unroll
        for (int i = 0; i < 16; ++i) { vals[i] = hw[t * 16 + i]; a = fmaxf(a, fabsf(vals[i])); }
        #pragma unroll
        for (int off = 32; off; off >>= 1) a = fmaxf(a, __shfl_xor(a, off));
        if (lane == 0) red[wid] = a;
        __syncthreads();
        float m = fmaxf(fmaxf(red[0], red[1]), fmaxf(red[2], red[3]));
        float scale = fmaxf(m, 1e-6f) / 127.0f;
        #pragma unroll
        for (int i = 0; i < 16; ++i) {
            float q = rintf(vals[i] / scale);
            q = fminf(fmaxf(q, -127.0f), 127.0f);
            wdq[t * 16 + i] = q * scale;
        }
    }
}

// ============ main: [0,256) gemm k-split 8 | [256,1280) halt partials
__global__ __launch_bounds__(256) void k_main(const float* __restrict__ x,
                                              const short* __restrict__ w1b,
                                              const unsigned int* __restrict__ bits_t,
                                              const int* __restrict__ conn,
                                              const unsigned short* __restrict__ tdq,
                                              const float* __restrict__ wdq,
                                              float* __restrict__ hpart,
                                              float* __restrict__ haltp) {
    int id = blockIdx.x;
    int t = threadIdx.x;
    int lane = t & 63;
    int wid = t >> 6;

    if (id < 256) {
        // ---- x(2048x4096) @ w1^T -> hpart[ks][b][h], bf16 MFMA 16x16x32, k-split 8
        int bx = id & 31, ks = id >> 5;
        int b0 = bx * 64 + wid * 16;
        int k0 = ks * 512;
        int row = lane & 15;
        int koff = (lane >> 4) * 8;

        const float* xp = x + (size_t)(b0 + row) * NN + k0 + koff;
        f32x4 acc[4] = {};

        #pragma unroll 4
        for (int kk = 0; kk < 16; ++kk) {
            const float* xa = xp + kk * 32;
            f32x4 a0 = *(const f32x4*)(xa);
            f32x4 a1 = *(const f32x4*)(xa + 4);
            bf16x8 af;
            af[0] = (short)f2bf(a0[0]); af[1] = (short)f2bf(a0[1]);
            af[2] = (short)f2bf(a0[2]); af[3] = (short)f2bf(a0[3]);
            af[4] = (short)f2bf(a1[0]); af[5] = (short)f2bf(a1[1]);
            af[6] = (short)f2bf(a1[2]); af[7] = (short)f2bf(a1[3]);
            #pragma unroll
            for (int h = 0; h < 4; ++h) {
                const short* wp = w1b + (size_t)(h * 16 + row) * NN + k0 + kk * 32 + koff;
                bf16x8 bf = *(const bf16x8*)wp;
                acc[h] = __builtin_amdgcn_mfma_f32_16x16x32_bf16(af, bf, acc[h], 0, 0, 0);
            }
        }
        #pragma unroll
        for (int h = 0; h < 4; ++h) {
            #pragma unroll
            for (int r = 0; r < 4; ++r) {
                int b = b0 + (lane >> 4) * 4 + r;     // C/D: row=(lane>>4)*4+reg
                int hh = h * 16 + (lane & 15);        // C/D: col=lane&15
                hpart[((size_t)ks * BB + b) * HH + hh] = acc[h][r];
            }
        }
    } else {
        // ---- halt partials: lane=b (coalesced bits_t reads), 32 m per wave
        int hid = id - 256;
        int hx = hid & 31, hy = hid >> 5;             // hy in [0,32)
        int b = hx * 64 + lane;
        int m0 = hy * 128 + wid * 32;
        float acc = 0.f;
        #pragma unroll 4
        for (int mi = 0; mi < 32; ++mi) {
            int m = m0 + mi;
            int addr = 0;
            #pragma unroll
            for (int k = 0; k < 8; ++k) {
                int c = conn[m * 8 + k];                               // uniform -> s_load
                unsigned int w = bits_t[(size_t)(c >> 5) * BB + b];    // coalesced, L1/L2-hit
                addr |= (int)((w >> (c & 31)) & 1u) << k;
            }
            acc += bf2f(tdq[(size_t)m * 256 + addr]) * wdq[m];
        }
        haltp[(size_t)(hy * 4 + wid) * BB + b] = acc;                  // coalesced
    }
}

// ============ finish: [0,512) engage reduce | [512,520) halt reduce
__global__ __launch_bounds__(256) void k_finish(const float* __restrict__ hpart,
                                                const float* __restrict__ b1,
                                                const float* __restrict__ w2,
                                                const float* __restrict__ b2,
                                                const float* __restrict__ haltp,
                                                const float* __restrict__ hb,
                                                float* __restrict__ out) {
    int id = blockIdx.x;
    int t = threadIdx.x;
    if (id < 512) {
        int h = t & 63;
        int b = id * 4 + (t >> 6);
        float s = 0.f;
        #pragma unroll
        for (int ks = 0; ks < 8; ++ks) s += hpart[((size_t)ks * BB + b) * HH + h];
        s += b1[h];
        s = fmaxf(s, 0.f);
        s *= w2[h];
        #pragma unroll
        for (int off = 32; off; off >>= 1) s += __shfl_xor(s, off);
        if (h == 0) out[b * 2] = s + b2[0];
    } else {
        int b = (id - 512) * 256 + t;
        float s = hb[0];
        #pragma unroll 8
        for (int j = 0; j < 128; ++j) s += haltp[(size_t)j * BB + b];  // coalesced
        out[b * 2 + 1] = s;
    }
}

extern "C" void kernel_launch(void* const* d_in, const int* in_sizes, int n_in,
                              void* d_out, int out_size, void* d_ws, size_t ws_size,
                              hipStream_t stream) {
    const float* x    = (const float*)d_in[0];
    const float* tab  = (const float*)d_in[1];
    const float* w1   = (const float*)d_in[2];
    const float* b1   = (const float*)d_in[3];
    const float* w2   = (const float*)d_in[4];
    const float* b2   = (const float*)d_in[5];
    const float* hw   = (const float*)d_in[6];
    const float* hb   = (const float*)d_in[7];
    const int*   conn = (const int*)d_in[8];
    float* out = (float*)d_out;

    char* ws = (char*)d_ws;
    unsigned short* tdq    = (unsigned short*)(ws);            // 2,097,152 B
    float*          wdq    = (float*)(ws + 2097152);           //    16,384 B
    unsigned int*   bits_t = (unsigned int*)(ws + 2113536);    // 1,048,576 B
    float*          hpart  = (float*)(ws + 3162112);           // 4,194,304 B
    float*          haltp  = (float*)(ws + 7356416);           // 1,048,576 B
    short*          w1b    = (short*)(ws + 8404992);           //   524,288 B (end 8,929,280)

    k_prep<<<2177, 256, 0, stream>>>(x, tab, w1, hw, bits_t, tdq, w1b, wdq);
    k_main<<<1280, 256, 0, stream>>>(x, w1b, bits_t, conn, tdq, wdq, hpart, haltp);
    k_finish<<<520, 256, 0, stream>>>(hpart, b1, w2, b2, haltp, hb, out);
}

// Round 5
// 56.867 us; speedup vs baseline: 2.1516x; 1.0431x over previous
//
#include <hip/hip_runtime.h>
#include <hip/hip_bf16.h>

#define BB 2048
#define NN 4096
#define MM 4096
#define HH 64
#define KSPLIT 16

using f32x4  = __attribute__((ext_vector_type(4))) float;
using bf16x8 = __attribute__((ext_vector_type(8))) short;

__device__ __forceinline__ unsigned short f2bf(float f) {
    union { float f; unsigned int u; } v; v.f = f;
    unsigned int r = ((v.u >> 16) & 1u) + 0x7FFFu;   // round-to-nearest-even
    return (unsigned short)((v.u + r) >> 16);
}

__device__ __forceinline__ float bf2f(unsigned short s) {
    union { unsigned int u; float f; } v; v.u = ((unsigned int)s) << 16;
    return v.f;
}

// ============ prep:
//   [0,1024)    bits pack via ballot (coalesced loads + transpose), 16 rows x 512 cols per block
//   [1024,2048) table quant -> bf16, 4 rows/block (1 row/wave)
//   [2048,2176) w1 -> bf16
//   2176        halt_w quant
__global__ __launch_bounds__(256) void k_prep(const float* __restrict__ x,
                                              const float* __restrict__ tab,
                                              const float* __restrict__ w1,
                                              const float* __restrict__ hw,
                                              unsigned int* __restrict__ bits_t,
                                              unsigned short* __restrict__ tdq,
                                              short* __restrict__ w1b,
                                              float* __restrict__ wdq) {
    int id = blockIdx.x;
    int t = threadIdx.x;
    int lane = t & 63;
    int wid = t >> 6;

    if (id < 1024) {
        // ---- sign bits: block = 16 rows x 512 cols; wave = 4 rows x 512 cols (8 ballots/row)
        __shared__ unsigned int tb[16][17];
        int rt = id >> 3;                 // 128 row-tiles of 16
        int cc8 = id & 7;                 // 8 col-chunks of 512
        int r0 = rt * 16, c0 = cc8 * 512;
        #pragma unroll
        for (int i = 0; i < 4; ++i) {
            int rl = wid * 4 + i;
            const float* xp = x + (size_t)(r0 + rl) * NN + c0;
            #pragma unroll
            for (int ch = 0; ch < 8; ++ch) {
                float v = xp[ch * 64 + lane];                  // coalesced 256B
                unsigned long long msk = __ballot(v > 0.0f);
                if (lane == 0) {
                    tb[rl][ch * 2]     = (unsigned int)msk;
                    tb[rl][ch * 2 + 1] = (unsigned int)(msk >> 32);
                }
            }
        }
        __syncthreads();
        int w = t >> 4, rl = t & 15;      // 16 words x 16 rows
        bits_t[(size_t)(c0 / 32 + w) * BB + r0 + rl] = tb[rl][w];
    } else if (id < 2048) {
        // ---- quantize ram_tables: one row per wave, f32x4 per lane
        int row = (id - 1024) * 4 + wid;
        f32x4 v = *(const f32x4*)(tab + (size_t)row * 256 + lane * 4);
        float a = fmaxf(fmaxf(fabsf(v[0]), fabsf(v[1])), fmaxf(fabsf(v[2]), fabsf(v[3])));
        #pragma unroll
        for (int off = 32; off; off >>= 1) a = fmaxf(a, __shfl_xor(a, off));
        float scale = fmaxf(a, 1e-6f) / 127.0f;
        short4 o;
        #pragma unroll
        for (int e = 0; e < 4; ++e) {
            float q = rintf(v[e] / scale);
            q = fminf(fmaxf(q, -127.0f), 127.0f);
            ((short*)&o)[e] = (short)f2bf(q * scale);
        }
        *(short4*)(tdq + (size_t)row * 256 + lane * 4) = o;
    } else if (id < 2176) {
        // ---- w1 -> bf16
        int base = (id - 2048) * 2048 + t * 8;
        f32x4 a0 = *(const f32x4*)(w1 + base);
        f32x4 a1 = *(const f32x4*)(w1 + base + 4);
        short4 o0, o1;
        o0.x = (short)f2bf(a0[0]); o0.y = (short)f2bf(a0[1]);
        o0.z = (short)f2bf(a0[2]); o0.w = (short)f2bf(a0[3]);
        o1.x = (short)f2bf(a1[0]); o1.y = (short)f2bf(a1[1]);
        o1.z = (short)f2bf(a1[2]); o1.w = (short)f2bf(a1[3]);
        *(short4*)(w1b + base) = o0;
        *(short4*)(w1b + base + 4) = o1;
    } else {
        // ---- quantize halt_w (4096 elems, one block), wdq stays f32
        __shared__ float red[4];
        float vals[16];
        float a = 0.f;
        #pragma unroll
        for (int i = 0; i < 16; ++i) { vals[i] = hw[t * 16 + i]; a = fmaxf(a, fabsf(vals[i])); }
        #pragma unroll
        for (int off = 32; off; off >>= 1) a = fmaxf(a, __shfl_xor(a, off));
        if (lane == 0) red[wid] = a;
        __syncthreads();
        float m = fmaxf(fmaxf(red[0], red[1]), fmaxf(red[2], red[3]));
        float scale = fmaxf(m, 1e-6f) / 127.0f;
        #pragma unroll
        for (int i = 0; i < 16; ++i) {
            float q = rintf(vals[i] / scale);
            q = fminf(fmaxf(q, -127.0f), 127.0f);
            wdq[t * 16 + i] = q * scale;
        }
    }
}

// ============ main: [0,512) gemm k-split 16 | [512,1536) halt partials (bits in LDS)
__global__ __launch_bounds__(256) void k_main(const float* __restrict__ x,
                                              const short* __restrict__ w1b,
                                              const unsigned int* __restrict__ bits_t,
                                              const int* __restrict__ conn,
                                              const unsigned short* __restrict__ tdq,
                                              const float* __restrict__ wdq,
                                              float* __restrict__ hpart,
                                              float* __restrict__ haltp) {
    int id = blockIdx.x;
    int t = threadIdx.x;
    int lane = t & 63;
    int wid = t >> 6;

    if (id < 512) {
        // ---- x(2048x4096) @ w1^T -> hpart[ks][b][h], bf16 MFMA 16x16x32, k-split 16
        int bx = id & 31, ks = id >> 5;
        int b0 = bx * 64 + wid * 16;
        int k0 = ks * 256;
        int row = lane & 15;
        int koff = (lane >> 4) * 8;

        const float* xp = x + (size_t)(b0 + row) * NN + k0 + koff;
        f32x4 acc[4] = {};

        #pragma unroll
        for (int kk = 0; kk < 8; ++kk) {
            const float* xa = xp + kk * 32;
            f32x4 a0 = *(const f32x4*)(xa);
            f32x4 a1 = *(const f32x4*)(xa + 4);
            bf16x8 af;
            af[0] = (short)f2bf(a0[0]); af[1] = (short)f2bf(a0[1]);
            af[2] = (short)f2bf(a0[2]); af[3] = (short)f2bf(a0[3]);
            af[4] = (short)f2bf(a1[0]); af[5] = (short)f2bf(a1[1]);
            af[6] = (short)f2bf(a1[2]); af[7] = (short)f2bf(a1[3]);
            #pragma unroll
            for (int h = 0; h < 4; ++h) {
                const short* wp = w1b + (size_t)(h * 16 + row) * NN + k0 + kk * 32 + koff;
                bf16x8 bf = *(const bf16x8*)wp;
                acc[h] = __builtin_amdgcn_mfma_f32_16x16x32_bf16(af, bf, acc[h], 0, 0, 0);
            }
        }
        #pragma unroll
        for (int h = 0; h < 4; ++h) {
            #pragma unroll
            for (int r = 0; r < 4; ++r) {
                int b = b0 + (lane >> 4) * 4 + r;     // C/D: row=(lane>>4)*4+reg
                int hh = h * 16 + (lane & 15);        // C/D: col=lane&15
                hpart[((size_t)ks * BB + b) * HH + hh] = acc[h][r];
            }
        }
    } else {
        // ---- halt partials: bits slice staged in LDS; lane=b; 32 m per wave
        __shared__ unsigned int lb[128][64];          // 32 KB
        int hid = id - 512;
        int hx = hid & 31, hy = hid >> 5;             // hy in [0,32)
        int b0 = hx * 64;
        for (int i = t; i < 128 * 64; i += 256) {
            int w = i >> 6, l = i & 63;
            lb[w][l] = bits_t[(size_t)w * BB + b0 + l];   // coalesced
        }
        __syncthreads();

        int m0 = hy * 128 + wid * 32;
        float acc = 0.f;
        #pragma unroll 4
        for (int mi = 0; mi < 32; ++mi) {
            int m = m0 + mi;
            int addr = 0;
            #pragma unroll
            for (int k = 0; k < 8; ++k) {
                int c = conn[m * 8 + k];              // uniform -> s_load
                unsigned int w = lb[c >> 5][lane];    // LDS, stride-1, conflict-free
                addr |= (int)((w >> (c & 31)) & 1u) << k;
            }
            acc += bf2f(tdq[(size_t)m * 256 + addr]) * wdq[m];
        }
        haltp[(size_t)(hy * 4 + wid) * BB + b0 + lane] = acc;   // coalesced
    }
}

// ============ finish: [0,512) engage reduce | [512,520) halt reduce
__global__ __launch_bounds__(256) void k_finish(const float* __restrict__ hpart,
                                                const float* __restrict__ b1,
                                                const float* __restrict__ w2,
                                                const float* __restrict__ b2,
                                                const float* __restrict__ haltp,
                                                const float* __restrict__ hb,
                                                float* __restrict__ out) {
    int id = blockIdx.x;
    int t = threadIdx.x;
    if (id < 512) {
        int h = t & 63;
        int b = id * 4 + (t >> 6);
        float s = 0.f;
        #pragma unroll
        for (int ks = 0; ks < KSPLIT; ++ks) s += hpart[((size_t)ks * BB + b) * HH + h];
        s += b1[h];
        s = fmaxf(s, 0.f);
        s *= w2[h];
        #pragma unroll
        for (int off = 32; off; off >>= 1) s += __shfl_xor(s, off);
        if (h == 0) out[b * 2] = s + b2[0];
    } else {
        int b = (id - 512) * 256 + t;
        float s = hb[0];
        #pragma unroll 8
        for (int j = 0; j < 128; ++j) s += haltp[(size_t)j * BB + b];  // coalesced
        out[b * 2 + 1] = s;
    }
}

extern "C" void kernel_launch(void* const* d_in, const int* in_sizes, int n_in,
                              void* d_out, int out_size, void* d_ws, size_t ws_size,
                              hipStream_t stream) {
    const float* x    = (const float*)d_in[0];
    const float* tab  = (const float*)d_in[1];
    const float* w1   = (const float*)d_in[2];
    const float* b1   = (const float*)d_in[3];
    const float* w2   = (const float*)d_in[4];
    const float* b2   = (const float*)d_in[5];
    const float* hw   = (const float*)d_in[6];
    const float* hb   = (const float*)d_in[7];
    const int*   conn = (const int*)d_in[8];
    float* out = (float*)d_out;

    char* ws = (char*)d_ws;
    unsigned short* tdq    = (unsigned short*)(ws);            //  2,097,152 B
    float*          wdq    = (float*)(ws + 2097152);           //     16,384 B
    unsigned int*   bits_t = (unsigned int*)(ws + 2113536);    //  1,048,576 B
    float*          hpart  = (float*)(ws + 3162112);           //  8,388,608 B (k-split 16)
    float*          haltp  = (float*)(ws + 11550720);          //  1,048,576 B
    short*          w1b    = (short*)(ws + 12599296);          //    524,288 B (end 13,123,584)

    k_prep<<<2177, 256, 0, stream>>>(x, tab, w1, hw, bits_t, tdq, w1b, wdq);
    k_main<<<1536, 256, 0, stream>>>(x, w1b, bits_t, conn, tdq, wdq, hpart, haltp);
    k_finish<<<520, 256, 0, stream>>>(hpart, b1, w2, b2, haltp, hb, out);
}

// Round 6
// 51.513 us; speedup vs baseline: 2.3753x; 1.1039x over previous
//
#include <hip/hip_runtime.h>
#include <hip/hip_bf16.h>

#define BB 2048
#define NN 4096
#define MM 4096
#define HH 64
#define KSPLIT 16

using f32x4  = __attribute__((ext_vector_type(4))) float;
using bf16x8 = __attribute__((ext_vector_type(8))) short;

__device__ __forceinline__ unsigned short f2bf(float f) {
    union { float f; unsigned int u; } v; v.f = f;
    unsigned int r = ((v.u >> 16) & 1u) + 0x7FFFu;   // round-to-nearest-even
    return (unsigned short)((v.u + r) >> 16);
}

// ============ k1: [0,512) gemm + sign-byte emit | [512,1536) table quant -> i8 | 1536 halt_w quant
__global__ __launch_bounds__(256) void k_gemm(const float* __restrict__ x,
                                              const float* __restrict__ w1,
                                              const float* __restrict__ tab,
                                              const float* __restrict__ hw,
                                              unsigned char* __restrict__ bits_b,
                                              signed char* __restrict__ tq8,
                                              float* __restrict__ tsc,
                                              float* __restrict__ wdq,
                                              float* __restrict__ hpart) {
    __shared__ short lB[64 * 256];    // 32 KB, XOR-swizzled bf16 B-tile
    __shared__ float red[4];
    int id = blockIdx.x;
    int t = threadIdx.x;
    int lane = t & 63;
    int wid = t >> 6;

    if (id < 512) {
        int bx = id & 31, ks = id >> 5;          // 32 b-tiles x 16 k-splits
        int b0g = bx * 64;
        int k0 = ks * 256;

        // ---- stage B: w1[h][k0..k0+256] f32 -> bf16 LDS, swizzle byte ^= (h&7)<<4
        for (int i = t; i < 64 * 64; i += 256) {
            int h = i >> 6, q = i & 63;
            f32x4 v = *(const f32x4*)(w1 + (size_t)h * NN + k0 + q * 4);
            short4 o;
            o.x = (short)f2bf(v[0]); o.y = (short)f2bf(v[1]);
            o.z = (short)f2bf(v[2]); o.w = (short)f2bf(v[3]);
            *(short4*)((char*)lB + (((h * 512) + q * 8) ^ ((h & 7) << 4))) = o;
        }
        __syncthreads();

        int row  = lane & 15;
        int grp  = lane >> 4;                    // 4 col-groups of 8
        int b    = b0g + wid * 16 + row;
        const float* xp = x + (size_t)b * NN + k0 + grp * 8;
        f32x4 acc[4] = {};

        #pragma unroll
        for (int kk = 0; kk < 8; ++kk) {
            const float* xa = xp + kk * 32;
            f32x4 a0 = *(const f32x4*)(xa);
            f32x4 a1 = *(const f32x4*)(xa + 4);
            bf16x8 af;
            af[0] = (short)f2bf(a0[0]); af[1] = (short)f2bf(a0[1]);
            af[2] = (short)f2bf(a0[2]); af[3] = (short)f2bf(a0[3]);
            af[4] = (short)f2bf(a1[0]); af[5] = (short)f2bf(a1[1]);
            af[6] = (short)f2bf(a1[2]); af[7] = (short)f2bf(a1[3]);

            // ---- sign byte for cols [k0+kk*32+grp*8, +8)
            unsigned int sb = 0;
            #pragma unroll
            for (int e = 0; e < 4; ++e) {
                sb |= (a0[e] > 0.0f ? 1u : 0u) << e;
                sb |= (a1[e] > 0.0f ? 1u : 0u) << (e + 4);
            }
            int g = ((k0 + kk * 32) >> 3) + grp;
            bits_b[(size_t)g * BB + b] = (unsigned char)sb;

            #pragma unroll
            for (int h = 0; h < 4; ++h) {
                int byteoff = (((h * 16 + row) * 512) + kk * 64 + grp * 16) ^ ((row & 7) << 4);
                bf16x8 bf = *(const bf16x8*)((const char*)lB + byteoff);
                acc[h] = __builtin_amdgcn_mfma_f32_16x16x32_bf16(af, bf, acc[h], 0, 0, 0);
            }
        }
        #pragma unroll
        for (int h = 0; h < 4; ++h) {
            #pragma unroll
            for (int r = 0; r < 4; ++r) {
                int bb = b0g + wid * 16 + grp * 4 + r;   // C/D: row=(lane>>4)*4+reg
                int hh = h * 16 + row;                    // C/D: col=lane&15
                hpart[((size_t)ks * BB + bb) * HH + hh] = acc[h][r];
            }
        }
    } else if (id < 1536) {
        // ---- quantize ram_tables -> i8 + scale; one row per wave
        int rowm = (id - 512) * 4 + wid;
        f32x4 v = *(const f32x4*)(tab + (size_t)rowm * 256 + lane * 4);
        float a = fmaxf(fmaxf(fabsf(v[0]), fabsf(v[1])), fmaxf(fabsf(v[2]), fabsf(v[3])));
        #pragma unroll
        for (int off = 32; off; off >>= 1) a = fmaxf(a, __shfl_xor(a, off));
        float scale = fmaxf(a, 1e-6f) / 127.0f;
        char4 o;
        #pragma unroll
        for (int e = 0; e < 4; ++e) {
            float q = rintf(v[e] / scale);
            q = fminf(fmaxf(q, -127.0f), 127.0f);
            ((signed char*)&o)[e] = (signed char)(int)q;
        }
        *(char4*)(tq8 + (size_t)rowm * 256 + lane * 4) = o;
        if (lane == 0) tsc[rowm] = scale;
    } else {
        // ---- quantize halt_w (4096 elems, one block)
        float vals[16];
        float a = 0.f;
        #pragma unroll
        for (int i = 0; i < 16; ++i) { vals[i] = hw[t * 16 + i]; a = fmaxf(a, fabsf(vals[i])); }
        #pragma unroll
        for (int off = 32; off; off >>= 1) a = fmaxf(a, __shfl_xor(a, off));
        if (lane == 0) red[wid] = a;
        __syncthreads();
        float m = fmaxf(fmaxf(red[0], red[1]), fmaxf(red[2], red[3]));
        float scale = fmaxf(m, 1e-6f) / 127.0f;
        #pragma unroll
        for (int i = 0; i < 16; ++i) {
            float q = rintf(vals[i] / scale);
            q = fminf(fmaxf(q, -127.0f), 127.0f);
            wdq[t * 16 + i] = q * scale;
        }
    }
}

// ============ k2: halt partials — bits (32KB) + int8 table tile (32KB) both in LDS
// grid 1024 = 32 b-tiles(64) x 32 m-chunks(128); 256 threads; 64 KB dynamic LDS
__global__ __launch_bounds__(256) void k_halt(const unsigned char* __restrict__ bits_b,
                                              const int* __restrict__ conn,
                                              const signed char* __restrict__ tq8,
                                              const float* __restrict__ tsc,
                                              const float* __restrict__ wdq,
                                              float* __restrict__ haltp) {
    extern __shared__ char sm[];
    unsigned char* lbits = (unsigned char*)sm;       // [512 g][64 b]
    signed char*   ltab  = (signed char*)(sm + 32768); // [128 m][256]

    int bx = blockIdx.x & 31, my = blockIdx.x >> 5;
    int b0 = bx * 64, m0 = my * 128;
    int t = threadIdx.x;

    for (int i = t; i < 2048; i += 256) {            // bits: 512 g x 4 uint4
        int g = i >> 2, q = i & 3;
        ((uint4*)lbits)[i] = *(const uint4*)(bits_b + (size_t)g * BB + b0 + q * 16);
    }
    for (int i = t; i < 2048; i += 256) {            // table tile: 32 KB straight copy
        ((uint4*)ltab)[i] = *(const uint4*)(tq8 + (size_t)m0 * 256 + i * 16);
    }
    __syncthreads();

    int lane = t & 63, wid = t >> 6;
    int grp = lane >> 4;                             // which m of the quad
    int bq  = lane & 15;                             // b-quad: bytes b0+bq*4..+4
    float acc0 = 0.f, acc1 = 0.f, acc2 = 0.f, acc3 = 0.f;

    #pragma unroll 2
    for (int qi = 0; qi < 8; ++qi) {
        int mb = m0 + wid * 32 + qi * 4;             // quad base (global m)
        int mloc = wid * 32 + qi * 4 + grp;          // local table row
        float vw0 = tsc[mb + 0] * wdq[mb + 0];
        float vw1 = tsc[mb + 1] * wdq[mb + 1];
        float vw2 = tsc[mb + 2] * wdq[mb + 2];
        float vw3 = tsc[mb + 3] * wdq[mb + 3];
        float vw = grp == 0 ? vw0 : grp == 1 ? vw1 : grp == 2 ? vw2 : vw3;

        unsigned int aq = 0;
        #pragma unroll
        for (int k = 0; k < 8; ++k) {
            int c0 = conn[(mb + 0) * 8 + k];
            int c1 = conn[(mb + 1) * 8 + k];
            int c2 = conn[(mb + 2) * 8 + k];
            int c3 = conn[(mb + 3) * 8 + k];
            int g  = grp == 0 ? (c0 >> 3) : grp == 1 ? (c1 >> 3) : grp == 2 ? (c2 >> 3) : (c3 >> 3);
            int sh = grp == 0 ? (c0 & 7)  : grp == 1 ? (c1 & 7)  : grp == 2 ? (c2 & 7)  : (c3 & 7);
            unsigned int w32 = *(const unsigned int*)(lbits + g * 64 + bq * 4);
            aq |= ((w32 >> sh) & 0x01010101u) << k;  // bit k of 4 addr bytes
        }
        const signed char* rowp = ltab + mloc * 256;
        float q0 = (float)rowp[aq & 255];
        float q1 = (float)rowp[(aq >> 8) & 255];
        float q2 = (float)rowp[(aq >> 16) & 255];
        float q3 = (float)rowp[aq >> 24];
        acc0 = fmaf(q0, vw, acc0); acc1 = fmaf(q1, vw, acc1);
        acc2 = fmaf(q2, vw, acc2); acc3 = fmaf(q3, vw, acc3);
    }

    // combine the 4 m-groups (lanes xor 16, xor 32)
    acc0 += __shfl_xor(acc0, 16); acc1 += __shfl_xor(acc1, 16);
    acc2 += __shfl_xor(acc2, 16); acc3 += __shfl_xor(acc3, 16);
    acc0 += __shfl_xor(acc0, 32); acc1 += __shfl_xor(acc1, 32);
    acc2 += __shfl_xor(acc2, 32); acc3 += __shfl_xor(acc3, 32);
    if (lane < 16) {
        float4 o = make_float4(acc0, acc1, acc2, acc3);
        *(float4*)(haltp + (size_t)(my * 4 + wid) * BB + b0 + bq * 4) = o;
    }
}

// ============ k3: [0,512) engage reduce | [512,520) halt reduce (128 slots)
__global__ __launch_bounds__(256) void k_finish(const float* __restrict__ hpart,
                                                const float* __restrict__ b1,
                                                const float* __restrict__ w2,
                                                const float* __restrict__ b2,
                                                const float* __restrict__ haltp,
                                                const float* __restrict__ hb,
                                                float* __restrict__ out) {
    int id = blockIdx.x;
    int t = threadIdx.x;
    if (id < 512) {
        int h = t & 63;
        int b = id * 4 + (t >> 6);
        float s = 0.f;
        #pragma unroll
        for (int ks = 0; ks < KSPLIT; ++ks) s += hpart[((size_t)ks * BB + b) * HH + h];
        s += b1[h];
        s = fmaxf(s, 0.f);
        s *= w2[h];
        #pragma unroll
        for (int off = 32; off; off >>= 1) s += __shfl_xor(s, off);
        if (h == 0) out[b * 2] = s + b2[0];
    } else {
        int b = (id - 512) * 256 + t;
        float s = hb[0];
        #pragma unroll 8
        for (int j = 0; j < 128; ++j) s += haltp[(size_t)j * BB + b];
        out[b * 2 + 1] = s;
    }
}

extern "C" void kernel_launch(void* const* d_in, const int* in_sizes, int n_in,
                              void* d_out, int out_size, void* d_ws, size_t ws_size,
                              hipStream_t stream) {
    const float* x    = (const float*)d_in[0];
    const float* tab  = (const float*)d_in[1];
    const float* w1   = (const float*)d_in[2];
    const float* b1   = (const float*)d_in[3];
    const float* w2   = (const float*)d_in[4];
    const float* b2   = (const float*)d_in[5];
    const float* hw   = (const float*)d_in[6];
    const float* hb   = (const float*)d_in[7];
    const int*   conn = (const int*)d_in[8];
    float* out = (float*)d_out;

    char* ws = (char*)d_ws;
    signed char*    tq8    = (signed char*)(ws);               //  1,048,576 B
    float*          tsc    = (float*)(ws + 1048576);           //     16,384 B
    float*          wdq    = (float*)(ws + 1064960);           //     16,384 B
    unsigned char*  bits_b = (unsigned char*)(ws + 1081344);   //  1,048,576 B
    float*          hpart  = (float*)(ws + 2129920);           //  8,388,608 B
    float*          haltp  = (float*)(ws + 10518528);          //  1,048,576 B (end 11,567,104)

    k_gemm<<<1537, 256, 0, stream>>>(x, w1, tab, hw, bits_b, tq8, tsc, wdq, hpart);
    k_halt<<<1024, 256, 65536, stream>>>(bits_b, conn, tq8, tsc, wdq, haltp);
    k_finish<<<520, 256, 0, stream>>>(hpart, b1, w2, b2, haltp, hb, out);
}

// Round 7
// 51.250 us; speedup vs baseline: 2.3875x; 1.0051x over previous
//
#include <hip/hip_runtime.h>
#include <hip/hip_bf16.h>

#define BB 2048
#define NN 4096
#define MM 4096
#define HH 64
#define KSPLIT 16

using f32x4  = __attribute__((ext_vector_type(4))) float;
using bf16x8 = __attribute__((ext_vector_type(8))) short;

__device__ __forceinline__ unsigned short f2bf(float f) {
    union { float f; unsigned int u; } v; v.f = f;
    unsigned int r = ((v.u >> 16) & 1u) + 0x7FFFu;   // round-to-nearest-even
    return (unsigned short)((v.u + r) >> 16);
}

// ============ k1: [0,512) LDS-staged gemm + sign-bytes | [512,1536) table quant -> i8 | 1536 halt_w quant
__global__ __launch_bounds__(256) void k_gemm(const float* __restrict__ x,
                                              const float* __restrict__ w1,
                                              const float* __restrict__ tab,
                                              const float* __restrict__ hw,
                                              unsigned char* __restrict__ bits_b,
                                              signed char* __restrict__ tq8,
                                              float* __restrict__ tsc,
                                              float* __restrict__ wdq,
                                              float* __restrict__ hpart) {
    __shared__ short lA[64 * 256];          // 32 KB swizzled bf16 x-tile
    __shared__ short lB[64 * 256];          // 32 KB swizzled bf16 w1-tile
    __shared__ unsigned char sby[2048];     // sign bytes [row][col8]
    __shared__ float red[4];
    int id = blockIdx.x;
    int t = threadIdx.x;
    int lane = t & 63;
    int wid = t >> 6;

    if (id < 512) {
        int bx = id & 31, ks = id >> 5;     // 32 b-tiles x 16 k-splits
        int b0 = bx * 64;
        int k0 = ks * 256;

        // ---- stage x-tile (coalesced: 32 lanes cover one 1KB row-slice), emit sign bytes
        #pragma unroll
        for (int i = 0; i < 8; ++i) {
            int c = t + i * 256;
            int row = c >> 5, col8 = c & 31;
            const float* p = x + (size_t)(b0 + row) * NN + k0 + col8 * 8;
            f32x4 a0 = *(const f32x4*)p;
            f32x4 a1 = *(const f32x4*)(p + 4);
            unsigned int s = 0;
            #pragma unroll
            for (int e = 0; e < 4; ++e) {
                s |= (a0[e] > 0.0f ? 1u : 0u) << e;
                s |= (a1[e] > 0.0f ? 1u : 0u) << (e + 4);
            }
            sby[c] = (unsigned char)s;
            bf16x8 v;
            v[0] = (short)f2bf(a0[0]); v[1] = (short)f2bf(a0[1]);
            v[2] = (short)f2bf(a0[2]); v[3] = (short)f2bf(a0[3]);
            v[4] = (short)f2bf(a1[0]); v[5] = (short)f2bf(a1[1]);
            v[6] = (short)f2bf(a1[2]); v[7] = (short)f2bf(a1[3]);
            *(bf16x8*)((char*)lA + ((row * 512 + col8 * 16) ^ ((row & 7) << 4))) = v;
        }
        // ---- stage w1-tile (same mapping)
        #pragma unroll
        for (int i = 0; i < 8; ++i) {
            int c = t + i * 256;
            int h = c >> 5, col8 = c & 31;
            const float* p = w1 + (size_t)h * NN + k0 + col8 * 8;
            f32x4 a0 = *(const f32x4*)p;
            f32x4 a1 = *(const f32x4*)(p + 4);
            bf16x8 v;
            v[0] = (short)f2bf(a0[0]); v[1] = (short)f2bf(a0[1]);
            v[2] = (short)f2bf(a0[2]); v[3] = (short)f2bf(a0[3]);
            v[4] = (short)f2bf(a1[0]); v[5] = (short)f2bf(a1[1]);
            v[6] = (short)f2bf(a1[2]); v[7] = (short)f2bf(a1[3]);
            *(bf16x8*)((char*)lB + ((h * 512 + col8 * 16) ^ ((h & 7) << 4))) = v;
        }
        __syncthreads();

        // ---- write sign bits, dword-coalesced (4 b's per dword)
        #pragma unroll
        for (int j = 0; j < 2; ++j) {
            int wI = t + j * 256;
            int g = wI >> 4, b4 = wI & 15;
            unsigned int d = 0;
            #pragma unroll
            for (int e = 0; e < 4; ++e)
                d |= (unsigned int)sby[(b4 * 4 + e) * 32 + g] << (e * 8);
            *(unsigned int*)(bits_b + (size_t)(ks * 32 + g) * BB + b0 + b4 * 4) = d;
        }

        // ---- MFMA: all operands from LDS
        int row = lane & 15, grp = lane >> 4;
        int R = wid * 16 + row;
        f32x4 acc[4] = {};
        #pragma unroll
        for (int kk = 0; kk < 8; ++kk) {
            bf16x8 af = *(const bf16x8*)((const char*)lA +
                          ((R * 512 + kk * 64 + grp * 16) ^ ((R & 7) << 4)));
            #pragma unroll
            for (int h = 0; h < 4; ++h) {
                int hr = h * 16 + row;
                bf16x8 bf = *(const bf16x8*)((const char*)lB +
                              ((hr * 512 + kk * 64 + grp * 16) ^ ((hr & 7) << 4)));
                acc[h] = __builtin_amdgcn_mfma_f32_16x16x32_bf16(af, bf, acc[h], 0, 0, 0);
            }
        }
        #pragma unroll
        for (int h = 0; h < 4; ++h) {
            #pragma unroll
            for (int r = 0; r < 4; ++r) {
                int bb = b0 + wid * 16 + grp * 4 + r;   // C/D: row=(lane>>4)*4+reg
                int hh = h * 16 + row;                   // C/D: col=lane&15
                hpart[((size_t)ks * BB + bb) * HH + hh] = acc[h][r];
            }
        }
    } else if (id < 1536) {
        // ---- quantize ram_tables -> i8 + scale; one row per wave
        int rowm = (id - 512) * 4 + wid;
        f32x4 v = *(const f32x4*)(tab + (size_t)rowm * 256 + lane * 4);
        float a = fmaxf(fmaxf(fabsf(v[0]), fabsf(v[1])), fmaxf(fabsf(v[2]), fabsf(v[3])));
        #pragma unroll
        for (int off = 32; off; off >>= 1) a = fmaxf(a, __shfl_xor(a, off));
        float scale = fmaxf(a, 1e-6f) / 127.0f;
        char4 o;
        #pragma unroll
        for (int e = 0; e < 4; ++e) {
            float q = rintf(v[e] / scale);
            q = fminf(fmaxf(q, -127.0f), 127.0f);
            ((signed char*)&o)[e] = (signed char)(int)q;
        }
        *(char4*)(tq8 + (size_t)rowm * 256 + lane * 4) = o;
        if (lane == 0) tsc[rowm] = scale;
    } else {
        // ---- quantize halt_w (4096 elems, one block)
        float vals[16];
        float a = 0.f;
        #pragma unroll
        for (int i = 0; i < 16; ++i) { vals[i] = hw[t * 16 + i]; a = fmaxf(a, fabsf(vals[i])); }
        #pragma unroll
        for (int off = 32; off; off >>= 1) a = fmaxf(a, __shfl_xor(a, off));
        if (lane == 0) red[wid] = a;
        __syncthreads();
        float m = fmaxf(fmaxf(red[0], red[1]), fmaxf(red[2], red[3]));
        float scale = fmaxf(m, 1e-6f) / 127.0f;
        #pragma unroll
        for (int i = 0; i < 16; ++i) {
            float q = rintf(vals[i] / scale);
            q = fminf(fmaxf(q, -127.0f), 127.0f);
            wdq[t * 16 + i] = q * scale;
        }
    }
}

// ============ k2: halt partials — bits (32KB) + int8 table tile (32KB) both in LDS
__global__ __launch_bounds__(256) void k_halt(const unsigned char* __restrict__ bits_b,
                                              const int* __restrict__ conn,
                                              const signed char* __restrict__ tq8,
                                              const float* __restrict__ tsc,
                                              const float* __restrict__ wdq,
                                              float* __restrict__ haltp) {
    extern __shared__ char sm[];
    unsigned char* lbits = (unsigned char*)sm;         // [512 g][64 b]
    signed char*   ltab  = (signed char*)(sm + 32768); // [128 m][256]

    int bx = blockIdx.x & 31, my = blockIdx.x >> 5;
    int b0 = bx * 64, m0 = my * 128;
    int t = threadIdx.x;

    for (int i = t; i < 2048; i += 256) {              // bits: 512 g x 4 uint4
        int g = i >> 2, q = i & 3;
        ((uint4*)lbits)[i] = *(const uint4*)(bits_b + (size_t)g * BB + b0 + q * 16);
    }
    for (int i = t; i < 2048; i += 256) {              // table tile: 32 KB
        ((uint4*)ltab)[i] = *(const uint4*)(tq8 + (size_t)m0 * 256 + i * 16);
    }
    __syncthreads();

    int lane = t & 63, wid = t >> 6;
    int grp = lane >> 4;
    int bq  = lane & 15;
    float acc0 = 0.f, acc1 = 0.f, acc2 = 0.f, acc3 = 0.f;

    #pragma unroll 2
    for (int qi = 0; qi < 8; ++qi) {
        int mb = m0 + wid * 32 + qi * 4;
        int mloc = wid * 32 + qi * 4 + grp;
        float vw0 = tsc[mb + 0] * wdq[mb + 0];
        float vw1 = tsc[mb + 1] * wdq[mb + 1];
        float vw2 = tsc[mb + 2] * wdq[mb + 2];
        float vw3 = tsc[mb + 3] * wdq[mb + 3];
        float vw = grp == 0 ? vw0 : grp == 1 ? vw1 : grp == 2 ? vw2 : vw3;

        unsigned int aq = 0;
        #pragma unroll
        for (int k = 0; k < 8; ++k) {
            int c0 = conn[(mb + 0) * 8 + k];
            int c1 = conn[(mb + 1) * 8 + k];
            int c2 = conn[(mb + 2) * 8 + k];
            int c3 = conn[(mb + 3) * 8 + k];
            int g  = grp == 0 ? (c0 >> 3) : grp == 1 ? (c1 >> 3) : grp == 2 ? (c2 >> 3) : (c3 >> 3);
            int sh = grp == 0 ? (c0 & 7)  : grp == 1 ? (c1 & 7)  : grp == 2 ? (c2 & 7)  : (c3 & 7);
            unsigned int w32 = *(const unsigned int*)(lbits + g * 64 + bq * 4);
            aq |= ((w32 >> sh) & 0x01010101u) << k;
        }
        const signed char* rowp = ltab + mloc * 256;
        float q0 = (float)rowp[aq & 255];
        float q1 = (float)rowp[(aq >> 8) & 255];
        float q2 = (float)rowp[(aq >> 16) & 255];
        float q3 = (float)rowp[aq >> 24];
        acc0 = fmaf(q0, vw, acc0); acc1 = fmaf(q1, vw, acc1);
        acc2 = fmaf(q2, vw, acc2); acc3 = fmaf(q3, vw, acc3);
    }

    acc0 += __shfl_xor(acc0, 16); acc1 += __shfl_xor(acc1, 16);
    acc2 += __shfl_xor(acc2, 16); acc3 += __shfl_xor(acc3, 16);
    acc0 += __shfl_xor(acc0, 32); acc1 += __shfl_xor(acc1, 32);
    acc2 += __shfl_xor(acc2, 32); acc3 += __shfl_xor(acc3, 32);
    if (lane < 16) {
        float4 o = make_float4(acc0, acc1, acc2, acc3);
        *(float4*)(haltp + (size_t)(my * 4 + wid) * BB + b0 + bq * 4) = o;
    }
}

// ============ k3: [0,512) engage reduce | [512,520) halt reduce (128 slots)
__global__ __launch_bounds__(256) void k_finish(const float* __restrict__ hpart,
                                                const float* __restrict__ b1,
                                                const float* __restrict__ w2,
                                                const float* __restrict__ b2,
                                                const float* __restrict__ haltp,
                                                const float* __restrict__ hb,
                                                float* __restrict__ out) {
    int id = blockIdx.x;
    int t = threadIdx.x;
    if (id < 512) {
        int h = t & 63;
        int b = id * 4 + (t >> 6);
        float s = 0.f;
        #pragma unroll
        for (int ks = 0; ks < KSPLIT; ++ks) s += hpart[((size_t)ks * BB + b) * HH + h];
        s += b1[h];
        s = fmaxf(s, 0.f);
        s *= w2[h];
        #pragma unroll
        for (int off = 32; off; off >>= 1) s += __shfl_xor(s, off);
        if (h == 0) out[b * 2] = s + b2[0];
    } else {
        int b = (id - 512) * 256 + t;
        float s = hb[0];
        #pragma unroll 8
        for (int j = 0; j < 128; ++j) s += haltp[(size_t)j * BB + b];
        out[b * 2 + 1] = s;
    }
}

extern "C" void kernel_launch(void* const* d_in, const int* in_sizes, int n_in,
                              void* d_out, int out_size, void* d_ws, size_t ws_size,
                              hipStream_t stream) {
    const float* x    = (const float*)d_in[0];
    const float* tab  = (const float*)d_in[1];
    const float* w1   = (const float*)d_in[2];
    const float* b1   = (const float*)d_in[3];
    const float* w2   = (const float*)d_in[4];
    const float* b2   = (const float*)d_in[5];
    const float* hw   = (const float*)d_in[6];
    const float* hb   = (const float*)d_in[7];
    const int*   conn = (const int*)d_in[8];
    float* out = (float*)d_out;

    char* ws = (char*)d_ws;
    signed char*    tq8    = (signed char*)(ws);               //  1,048,576 B
    float*          tsc    = (float*)(ws + 1048576);           //     16,384 B
    float*          wdq    = (float*)(ws + 1064960);           //     16,384 B
    unsigned char*  bits_b = (unsigned char*)(ws + 1081344);   //  1,048,576 B
    float*          hpart  = (float*)(ws + 2129920);           //  8,388,608 B
    float*          haltp  = (float*)(ws + 10518528);          //  1,048,576 B (end 11,567,104)

    k_gemm<<<1537, 256, 0, stream>>>(x, w1, tab, hw, bits_b, tq8, tsc, wdq, hpart);
    k_halt<<<1024, 256, 65536, stream>>>(bits_b, conn, tq8, tsc, wdq, haltp);
    k_finish<<<520, 256, 0, stream>>>(hpart, b1, w2, b2, haltp, hb, out);
}